// Round 2
// baseline (99.598 us; speedup 1.0000x reference)
//
#include <hip/hip_runtime.h>

#define LL 64
#define NN 20
#define DTC 0.01f
#define NOISEC 1e-3f
#define LN2C 0.69314718056f

typedef __attribute__((ext_vector_type(8))) short short8x;
typedef __attribute__((ext_vector_type(4))) float f32x4;
typedef __attribute__((ext_vector_type(4))) int v4i;

// pack two floats to bf16x2 with round-to-nearest-even (manual, no HIP types)
__device__ __forceinline__ unsigned bf16r(float x) {
    union { float f; unsigned u; } a; a.f = x;
    return (a.u + (0x7fffu + ((a.u >> 16) & 1u))) >> 16;
}
__device__ __forceinline__ unsigned pk_bf16(float x, float y) {
    return bf16r(x) | (bf16r(y) << 16);
}

// Single-step row_shr:D (D=1..15), bound_ctrl zero-fill, applied to all 4
// dwords of a bf16x8 fragment. Bv[d](nh,qd) = Bv[0](nh-d,qd), 0 for nh<d.
// 15 INDEPENDENT ops (R13) instead of a serial chain.
template<int CTRL>
__device__ __forceinline__ short8x dpp_shr(short8x v) {
    v4i p = __builtin_bit_cast(v4i, v);
    v4i q;
    q.x = __builtin_amdgcn_update_dpp(0, p.x, CTRL, 0xf, 0xf, true);
    q.y = __builtin_amdgcn_update_dpp(0, p.y, CTRL, 0xf, 0xf, true);
    q.z = __builtin_amdgcn_update_dpp(0, p.z, CTRL, 0xf, 0xf, true);
    q.w = __builtin_amdgcn_update_dpp(0, p.w, CTRL, 0xf, 0xf, true);
    return __builtin_bit_cast(short8x, q);
}

// R14: derive the tile-1 A-fragment (table shift -16) from two tile-0
// fragments in-register. Identity (validated algebraically from the R8/R9
// indexing): A1v[d] = { lanes 0-31: A0v[d+1] @ lane+32,
//                       lanes 32-63: A0v[d]   @ lane-32 }.
// v_permlane32_swap_b32(a=A0v[d+1], b=A0v[d]) yields s[0]={a.lo,b.lo},
// s[1]={a.hi,b.hi}; select s[0] on hi lanes (its hi = b.lo = A0v[d].lo) and
// s[1] on lo lanes (its lo = a.hi = A0v[d+1].hi). 1 permlane + 1 cndmask
// per dword replaces 1/4 of a ds_read_b128 on the contended LDS pipe.
__device__ __forceinline__ short8x derive_m16(short8x dNext, short8x dCur, bool hi32) {
    v4i a = __builtin_bit_cast(v4i, dNext);
    v4i b = __builtin_bit_cast(v4i, dCur);
    v4i r;
    { auto s = __builtin_amdgcn_permlane32_swap(a.x, b.x, false, false); r.x = hi32 ? s[0] : s[1]; }
    { auto s = __builtin_amdgcn_permlane32_swap(a.y, b.y, false, false); r.y = hi32 ? s[0] : s[1]; }
    { auto s = __builtin_amdgcn_permlane32_swap(a.z, b.z, false, false); r.z = hi32 ? s[0] : s[1]; }
    { auto s = __builtin_amdgcn_permlane32_swap(a.w, b.w, false, false); r.w = hi32 ? s[0] : s[1]; }
    return __builtin_bit_cast(short8x, r);
}

// R14: back to ONE wave (64 thr) per channel c = b*64+l, NO barriers (R13's
// 2-wave split + barrier was NEUTRAL: per-CU LDS traffic and per-step chain
// were invariant -> occupancy was not the lever; LDS traffic is).
// Block-Toeplitz MFMA (validated R8/R9): Qn[32I+i] = sum_d sum_k
// G_d[i][k]*Qsrc[32(I-d)+k], G_d[i][k] = g(32d+i-k), g = DT*q_n reversed,
// zero for negative arg. gt copy kk pos w holds r[w+kk] so every A-read is
// one aligned ds_read_b128; Q zero-prefix handles the B boundary.
// LDS reads/step: 1 (B) + 16 (A0) + 1 (A1[15]) = 18 ds_read_b128, vs 33
// before -- tile-1 A-fragments d=0..14 derived via permlane32_swap (VALU),
// B-fragments d>=1 via independent DPP row_shr:d.
__global__ __launch_bounds__(64, 1) void outage_kernel(
    const float* __restrict__ pathloss,
    const float* __restrict__ powers,
    float* __restrict__ out)
{
    __shared__ __align__(16) unsigned short gt[2][8][544];  // 8 shifted copies, ping-pong
    __shared__ __align__(16) unsigned short Qb[2][1024];    // [0,512)=zeros, [512,1024)=data

    const int lane = threadIdx.x;
    const int c = blockIdx.x, b = c >> 6, l = c & 63;
    const int nh = lane & 15;          // MFMA m / n index
    const int qd = lane >> 4;          // MFMA quad (k-group)
    const bool hi32 = (lane >= 32);

    // ---- inline prep: rowsum + diag of pathloss row l (coalesced) ----
    const float pl = pathloss[l * LL + lane];
    float rs = pl;
    #pragma unroll
    for (int mk = 1; mk < 64; mk <<= 1) rs += __shfl_xor(rs, mk, 64);
    const float dg   = __shfl(pl, l, 64);
    const float dsum = rs - dg;

    // per-lane time constants, tau = 8*lane + u
    float P2[8], P1[8];
    #pragma unroll
    for (int u = 0; u < 8; ++u) {
        P2[u] = exp2f((8 * lane + u) * DTC);
        P1[u] = P2[u] - 1.f;
    }

    // zero Q prefixes (1 KiB each) and gt tails [512,544) of both buffers
    *((uint4*)&Qb[0][0] + lane) = uint4{0u, 0u, 0u, 0u};
    *((uint4*)&Qb[1][0] + lane) = uint4{0u, 0u, 0u, 0u};
    {
        const int bb = lane >> 5, w = lane & 31;
        #pragma unroll
        for (int k = 0; k < 8; ++k) gt[bb][k][512 + w] = 0;
    }

    // Q0(tau) = 1 - exp(-(2^{tau*DT}-1)*s0), bf16 into Qb[0]
    const float p0 = powers[(b * NN + 0) * LL + l];
    const float s0 = dg * p0 / (p0 * dsum + NOISEC);
    float q7;
    {
        float v[8];
        #pragma unroll
        for (int u = 0; u < 8; ++u) v[u] = 1.f - expf(-P1[u] * s0);
        q7 = v[7];                                  // lane 63: Q0[511]
        uint4 d4 = { pk_bf16(v[0], v[1]), pk_bf16(v[2], v[3]),
                     pk_bf16(v[4], v[5]), pk_bf16(v[6], v[7]) };
        *(uint4*)&Qb[0][512 + 8 * lane] = d4;
    }

    const float p1v = powers[(b * NN + 1) * LL + l];
    float lossCh = 1.f + p0 + (p1v + 1.f) * q7;     // only lane 63's is used

    // fill the 8 shifted copies of r[tau] = DT*q_n(tau) for a step into buf
    auto fill_g = [&](int buf, float p) {
        float s  = dg * p / (p * dsum + NOISEC);
        float cm = s * LN2C * DTC;
        unsigned F[8];                               // F[0..3] own pairs, F[4..7] neighbor
        #pragma unroll
        for (int w = 0; w < 4; ++w) {
            float a  = expf(-P1[2 * w] * s) * P2[2 * w] * cm;
            float bb = expf(-P1[2 * w + 1] * s) * P2[2 * w + 1] * cm;
            F[w] = pk_bf16(a, bb);
        }
        #pragma unroll
        for (int w = 0; w < 4; ++w) {
            unsigned t = (unsigned)__shfl_down((int)F[w], 1, 64);
            F[4 + w] = (lane == 63) ? 0u : t;       // tau >= 512 -> 0
        }
        unsigned E[7];                               // odd-phase pairs
        #pragma unroll
        for (int j = 0; j < 7; ++j) E[j] = (F[j] >> 16) | (F[j + 1] << 16);
        #pragma unroll
        for (int k = 0; k < 8; ++k) {               // copy k pos 8L+w holds r[8L+w+k]
            uint4 d4;
            if ((k & 1) == 0) d4 = uint4{F[k / 2], F[k / 2 + 1], F[k / 2 + 2], F[k / 2 + 3]};
            else              d4 = uint4{E[k / 2], E[k / 2 + 1], E[k / 2 + 2], E[k / 2 + 3]};
            *(uint4*)&gt[buf][k][8 * lane] = d4;
        }
    };
    fill_g(1, p1v);                                 // g-table for step n=1

    const int kk    = (7 - nh) & 7;                 // this lane's copy index
    const int baseA = 511 - nh + 8 * qd - kk;       // == 0 mod 8 (16B aligned)
    const int baseB = 512 + 32 * nh + 8 * qd;
    const int dstw  = 512 + 32 * nh + 4 * qd;       // +16 for M-tile 1

    float pnext = powers[(b * NN + 2) * LL + l];    // pw[n+1] entering n=1

    for (int n = 1; n < NN; ++n) {
        const unsigned short* psrc = &Qb[(n + 1) & 1][0];   // == (n-1)&1
        const unsigned short* pg   = &gt[n & 1][kk][0];
        unsigned short* pdst       = &Qb[n & 1][0];

        // issue next-next power load early (lands during this step's work)
        float pfut = 0.f;
        if (n <= NN - 3) pfut = powers[(b * NN + n + 2) * LL + l];

        // ---- B: one ds_read_b128 + 15 INDEPENDENT row_shr:d derivations ----
        short8x Bv[16];
        Bv[0]  = *(const short8x*)&psrc[baseB];
        Bv[1]  = dpp_shr<0x111>(Bv[0]);
        Bv[2]  = dpp_shr<0x112>(Bv[0]);
        Bv[3]  = dpp_shr<0x113>(Bv[0]);
        Bv[4]  = dpp_shr<0x114>(Bv[0]);
        Bv[5]  = dpp_shr<0x115>(Bv[0]);
        Bv[6]  = dpp_shr<0x116>(Bv[0]);
        Bv[7]  = dpp_shr<0x117>(Bv[0]);
        Bv[8]  = dpp_shr<0x118>(Bv[0]);
        Bv[9]  = dpp_shr<0x119>(Bv[0]);
        Bv[10] = dpp_shr<0x11A>(Bv[0]);
        Bv[11] = dpp_shr<0x11B>(Bv[0]);
        Bv[12] = dpp_shr<0x11C>(Bv[0]);
        Bv[13] = dpp_shr<0x11D>(Bv[0]);
        Bv[14] = dpp_shr<0x11E>(Bv[0]);
        Bv[15] = dpp_shr<0x11F>(Bv[0]);

        // ---- A operands tile 0: 16 x ds_read_b128; tile 1 d=15 boundary
        //      fragment read directly (its derivation would need A0v[16],
        //      whose low lanes index before the table) ----
        short8x A0v[16];
        #pragma unroll
        for (int d = 0; d < 16; ++d) A0v[d] = *(const short8x*)&pg[baseA - 32 * d];
        const short8x A15 = *(const short8x*)&pg[baseA - 32 * 15 - 16];

        // ---- fill g-table for step n+1 (independent buffer) under the
        //      MFMA shadow; uses pnext loaded one iteration ago ----
        if (n < NN - 1) fill_g((n + 1) & 1, pnext);

        // ---- 4 independent MFMA chains; tile-1 A-fragments derived on the
        //      fly (keeps A1 liveness at 2 fragments) ----
        f32x4 acc0a = {0.f, 0.f, 0.f, 0.f}, acc0b = {0.f, 0.f, 0.f, 0.f};
        f32x4 acc1a = {0.f, 0.f, 0.f, 0.f}, acc1b = {0.f, 0.f, 0.f, 0.f};
        #pragma unroll
        for (int d = 0; d < 16; d += 2) {
            short8x A1e = derive_m16(A0v[d + 1], A0v[d], hi32);
            short8x A1o;
            if (d < 14) A1o = derive_m16(A0v[d + 2], A0v[d + 1], hi32);
            else        A1o = A15;
            acc0a = __builtin_amdgcn_mfma_f32_16x16x32_bf16(A0v[d],     Bv[d],     acc0a, 0, 0, 0);
            acc1a = __builtin_amdgcn_mfma_f32_16x16x32_bf16(A1e,        Bv[d],     acc1a, 0, 0, 0);
            acc0b = __builtin_amdgcn_mfma_f32_16x16x32_bf16(A0v[d + 1], Bv[d + 1], acc0b, 0, 0, 0);
            acc1b = __builtin_amdgcn_mfma_f32_16x16x32_bf16(A1o,        Bv[d + 1], acc1b, 0, 0, 0);
        }
        f32x4 acc0 = acc0a + acc0b;
        f32x4 acc1 = acc1a + acc1b;

        // write Qn (bf16): lane holds rows 4qd..4qd+3 of both M-tiles, col nh
        *(uint2*)&pdst[dstw]      = uint2{pk_bf16(acc0.x, acc0.y), pk_bf16(acc0.z, acc0.w)};
        *(uint2*)&pdst[dstw + 16] = uint2{pk_bf16(acc1.x, acc1.y), pk_bf16(acc1.z, acc1.w)};

        // loss tap: lane 63 acc1.w == Qn[511] (row 31, col 15), fp32 precision
        float wgt = (n < NN - 1) ? (pnext + 1.f) : 1.f;   // pnext == pw[n+1]
        lossCh += wgt * acc1.w;
        pnext = pfut;
    }

    if (lane == 63) atomicAdd(out, lossCh);
}

extern "C" void kernel_launch(void* const* d_in, const int* in_sizes, int n_in,
                              void* d_out, int out_size, void* d_ws, size_t ws_size,
                              hipStream_t stream) {
    const float* pathloss = (const float*)d_in[0];
    const float* powers   = (const float*)d_in[1];
    float* outp = (float*)d_out;

    (void)hipMemsetAsync(d_out, 0, sizeof(float) * out_size, stream);
    outage_kernel<<<16 * LL, 64, 0, stream>>>(pathloss, powers, outp);
}

// Round 3
// 91.111 us; speedup vs baseline: 1.0932x; 1.0932x over previous
//
#include <hip/hip_runtime.h>

#define LL 64
#define NN 20
#define DTC 0.01f
#define NOISEC 1e-3f
#define LN2C 0.69314718056f

typedef __attribute__((ext_vector_type(8))) short short8x;
typedef __attribute__((ext_vector_type(4))) float f32x4;
typedef __attribute__((ext_vector_type(4))) int v4i;

// pack two floats to bf16x2 with round-to-nearest-even (manual, no HIP types)
__device__ __forceinline__ unsigned bf16r(float x) {
    union { float f; unsigned u; } a; a.f = x;
    return (a.u + (0x7fffu + ((a.u >> 16) & 1u))) >> 16;
}
__device__ __forceinline__ unsigned pk_bf16(float x, float y) {
    return bf16r(x) | (bf16r(y) << 16);
}

// Single-step row_shr:D (D=1..15), bound_ctrl zero-fill, applied to all 4
// dwords of a bf16x8 fragment. Bv[d](nh,qd) = Bv[0](nh-d,qd), 0 for nh<d.
// 15 INDEPENDENT ops (validated R13/R14).
template<int CTRL>
__device__ __forceinline__ short8x dpp_shr(short8x v) {
    v4i p = __builtin_bit_cast(v4i, v);
    v4i q;
    q.x = __builtin_amdgcn_update_dpp(0, p.x, CTRL, 0xf, 0xf, true);
    q.y = __builtin_amdgcn_update_dpp(0, p.y, CTRL, 0xf, 0xf, true);
    q.z = __builtin_amdgcn_update_dpp(0, p.z, CTRL, 0xf, 0xf, true);
    q.w = __builtin_amdgcn_update_dpp(0, p.w, CTRL, 0xf, 0xf, true);
    return __builtin_bit_cast(short8x, q);
}

// R15: one wave (64 thr) per channel, NO barriers. Post-mortem of R13/R14:
// R13 (2 waves, barrier, same totals) neutral; R14 (-15 DS reads, +100
// permlane VALU) regressed with wall growing 1:1 with VALU cycles -> kernel
// is single-wave issue+latency bound; permlane is expensive; DS reads are
// cheap. So: (a) R14 derive REVERTED (32 direct A reads, latency hidden
// under fill_g's VALU); (b) B-read for step n+1 issued at END of step n
// right after the Qn ds_write (same-wave in-order DS), killing the ~120cy
// read->DPP stall that opened every step; (c) MFMA restructured from 4
// chains x depth 8 to 8 chains x depth 4 (halves dependent-MFMA latency).
// Block-Toeplitz MFMA (validated R8/R9): Qn[32I+i] = sum_d sum_k
// G_d[i][k]*Qsrc[32(I-d)+k], G_d[i][k] = g(32d+i-k), g = DT*q_n reversed,
// zero for negative arg. gt copy kk pos w holds r[w+kk] so every A-read is
// one aligned ds_read_b128; DPP bound_ctrl zeros give the B boundary.
__global__ __launch_bounds__(64, 1) void outage_kernel(
    const float* __restrict__ pathloss,
    const float* __restrict__ powers,
    float* __restrict__ out)
{
    __shared__ __align__(16) unsigned short gt[2][8][544];  // 8 shifted copies, ping-pong
    __shared__ __align__(16) unsigned short Qb[2][1024];    // [0,512)=zeros, [512,1024)=data

    const int lane = threadIdx.x;
    const int c = blockIdx.x, b = c >> 6, l = c & 63;
    const int nh = lane & 15;          // MFMA m / n index
    const int qd = lane >> 4;          // MFMA quad (k-group)

    // ---- inline prep: rowsum + diag of pathloss row l (coalesced) ----
    const float pl = pathloss[l * LL + lane];
    float rs = pl;
    #pragma unroll
    for (int mk = 1; mk < 64; mk <<= 1) rs += __shfl_xor(rs, mk, 64);
    const float dg   = __shfl(pl, l, 64);
    const float dsum = rs - dg;

    // per-lane time constants, tau = 8*lane + u
    float P2[8], P1[8];
    #pragma unroll
    for (int u = 0; u < 8; ++u) {
        P2[u] = exp2f((8 * lane + u) * DTC);
        P1[u] = P2[u] - 1.f;
    }

    // zero Q prefixes (1 KiB each) and gt tails [512,544) of both buffers
    *((uint4*)&Qb[0][0] + lane) = uint4{0u, 0u, 0u, 0u};
    *((uint4*)&Qb[1][0] + lane) = uint4{0u, 0u, 0u, 0u};
    {
        const int bb = lane >> 5, w = lane & 31;
        #pragma unroll
        for (int k = 0; k < 8; ++k) gt[bb][k][512 + w] = 0;
    }

    // Q0(tau) = 1 - exp(-(2^{tau*DT}-1)*s0), bf16 into Qb[0]
    const float p0 = powers[(b * NN + 0) * LL + l];
    const float s0 = dg * p0 / (p0 * dsum + NOISEC);
    float q7;
    {
        float v[8];
        #pragma unroll
        for (int u = 0; u < 8; ++u) v[u] = 1.f - expf(-P1[u] * s0);
        q7 = v[7];                                  // lane 63: Q0[511]
        uint4 d4 = { pk_bf16(v[0], v[1]), pk_bf16(v[2], v[3]),
                     pk_bf16(v[4], v[5]), pk_bf16(v[6], v[7]) };
        *(uint4*)&Qb[0][512 + 8 * lane] = d4;
    }

    const float p1v = powers[(b * NN + 1) * LL + l];
    float lossCh = 1.f + p0 + (p1v + 1.f) * q7;     // only lane 63's is used

    // fill the 8 shifted copies of r[tau] = DT*q_n(tau) for a step into buf
    auto fill_g = [&](int buf, float p) {
        float s  = dg * p / (p * dsum + NOISEC);
        float cm = s * LN2C * DTC;
        unsigned F[8];                               // F[0..3] own pairs, F[4..7] neighbor
        #pragma unroll
        for (int w = 0; w < 4; ++w) {
            float a  = expf(-P1[2 * w] * s) * P2[2 * w] * cm;
            float bb = expf(-P1[2 * w + 1] * s) * P2[2 * w + 1] * cm;
            F[w] = pk_bf16(a, bb);
        }
        #pragma unroll
        for (int w = 0; w < 4; ++w) {
            unsigned t = (unsigned)__shfl_down((int)F[w], 1, 64);
            F[4 + w] = (lane == 63) ? 0u : t;       // tau >= 512 -> 0
        }
        unsigned E[7];                               // odd-phase pairs
        #pragma unroll
        for (int j = 0; j < 7; ++j) E[j] = (F[j] >> 16) | (F[j + 1] << 16);
        #pragma unroll
        for (int k = 0; k < 8; ++k) {               // copy k pos 8L+w holds r[8L+w+k]
            uint4 d4;
            if ((k & 1) == 0) d4 = uint4{F[k / 2], F[k / 2 + 1], F[k / 2 + 2], F[k / 2 + 3]};
            else              d4 = uint4{E[k / 2], E[k / 2 + 1], E[k / 2 + 2], E[k / 2 + 3]};
            *(uint4*)&gt[buf][k][8 * lane] = d4;
        }
    };
    fill_g(1, p1v);                                 // g-table for step n=1

    const int kk    = (7 - nh) & 7;                 // this lane's copy index
    const int baseA = 511 - nh + 8 * qd - kk;       // == 0 mod 8 (16B aligned)
    const int baseB = 512 + 32 * nh + 8 * qd;
    const int dstw  = 512 + 32 * nh + 4 * qd;       // +16 for M-tile 1

    float pnext = powers[(b * NN + 2) * LL + l];    // pw[n+1] entering n=1

    // B-fragment preload for step n=1 (after Q0 store; in-order DS)
    short8x Bv0 = *(const short8x*)&Qb[0][baseB];

    for (int n = 1; n < NN; ++n) {
        const unsigned short* pg = &gt[n & 1][kk][0];
        unsigned short* pdst     = &Qb[n & 1][0];

        // issue next-next power load early (lands during this step's work)
        float pfut = 0.f;
        if (n <= NN - 3) pfut = powers[(b * NN + n + 2) * LL + l];

        // ---- B: preloaded Bv0 + 15 INDEPENDENT row_shr:d derivations ----
        short8x Bv[16];
        Bv[0]  = Bv0;
        Bv[1]  = dpp_shr<0x111>(Bv0);
        Bv[2]  = dpp_shr<0x112>(Bv0);
        Bv[3]  = dpp_shr<0x113>(Bv0);
        Bv[4]  = dpp_shr<0x114>(Bv0);
        Bv[5]  = dpp_shr<0x115>(Bv0);
        Bv[6]  = dpp_shr<0x116>(Bv0);
        Bv[7]  = dpp_shr<0x117>(Bv0);
        Bv[8]  = dpp_shr<0x118>(Bv0);
        Bv[9]  = dpp_shr<0x119>(Bv0);
        Bv[10] = dpp_shr<0x11A>(Bv0);
        Bv[11] = dpp_shr<0x11B>(Bv0);
        Bv[12] = dpp_shr<0x11C>(Bv0);
        Bv[13] = dpp_shr<0x11D>(Bv0);
        Bv[14] = dpp_shr<0x11E>(Bv0);
        Bv[15] = dpp_shr<0x11F>(Bv0);

        // ---- A operands, both tiles (32 x ds_read_b128); latency hides
        //      under fill_g's VALU below ----
        short8x A0v[16], A1v[16];
        #pragma unroll
        for (int d = 0; d < 16; ++d) {
            A0v[d] = *(const short8x*)&pg[baseA - 32 * d];
            A1v[d] = *(const short8x*)&pg[baseA - 32 * d - 16];
        }

        // ---- fill g-table for step n+1 (independent buffer) under the
        //      A-read / MFMA shadow; uses pnext loaded one iteration ago ----
        if (n < NN - 1) fill_g((n + 1) & 1, pnext);

        // ---- 8 independent MFMA chains, depth 4 each (was 4 x depth 8) ----
        f32x4 c0[4], c1[4];
        #pragma unroll
        for (int j = 0; j < 4; ++j) { c0[j] = f32x4{0.f,0.f,0.f,0.f}; c1[j] = f32x4{0.f,0.f,0.f,0.f}; }
        #pragma unroll
        for (int d = 0; d < 16; ++d) {
            c0[d & 3] = __builtin_amdgcn_mfma_f32_16x16x32_bf16(A0v[d], Bv[d], c0[d & 3], 0, 0, 0);
            c1[d & 3] = __builtin_amdgcn_mfma_f32_16x16x32_bf16(A1v[d], Bv[d], c1[d & 3], 0, 0, 0);
        }
        f32x4 acc0 = (c0[0] + c0[1]) + (c0[2] + c0[3]);
        f32x4 acc1 = (c1[0] + c1[1]) + (c1[2] + c1[3]);

        // write Qn (bf16): lane holds rows 4qd..4qd+3 of both M-tiles, col nh
        *(uint2*)&pdst[dstw]      = uint2{pk_bf16(acc0.x, acc0.y), pk_bf16(acc0.z, acc0.w)};
        *(uint2*)&pdst[dstw + 16] = uint2{pk_bf16(acc1.x, acc1.y), pk_bf16(acc1.z, acc1.w)};

        // ---- preload next step's B-fragment NOW (same-wave in-order DS:
        //      read issues after the writes above, sees fresh Qn; its
        //      latency hides under loss tap + loop bookkeeping) ----
        if (n < NN - 1) Bv0 = *(const short8x*)&pdst[baseB];

        // loss tap: lane 63 acc1.w == Qn[511] (row 31, col 15), fp32 precision
        float wgt = (n < NN - 1) ? (pnext + 1.f) : 1.f;   // pnext == pw[n+1]
        lossCh += wgt * acc1.w;
        pnext = pfut;
    }

    if (lane == 63) atomicAdd(out, lossCh);
}

extern "C" void kernel_launch(void* const* d_in, const int* in_sizes, int n_in,
                              void* d_out, int out_size, void* d_ws, size_t ws_size,
                              hipStream_t stream) {
    const float* pathloss = (const float*)d_in[0];
    const float* powers   = (const float*)d_in[1];
    float* outp = (float*)d_out;

    (void)hipMemsetAsync(d_out, 0, sizeof(float) * out_size, stream);
    outage_kernel<<<16 * LL, 64, 0, stream>>>(pathloss, powers, outp);
}

// Round 4
// 85.593 us; speedup vs baseline: 1.1636x; 1.0645x over previous
//
#include <hip/hip_runtime.h>

#define LL 64
#define NN 20
#define DTC 0.01f
#define NOISEC 1e-3f
#define LN2C 0.69314718056f
#define LOG2E 1.44269504089f

typedef __attribute__((ext_vector_type(8))) short short8x;
typedef __attribute__((ext_vector_type(4))) float f32x4;
typedef __attribute__((ext_vector_type(4))) int v4i;

// R16: pack two f32 -> bf16x2 in ONE instruction (RNE), replacing ~7 bit-ops.
// gfx950 has v_cvt_pk_bf16_f32 (no builtin; inline asm per platform guide).
__device__ __forceinline__ unsigned cvt_pk_bf16(float x, float y) {
    unsigned r;
    asm("v_cvt_pk_bf16_f32 %0, %1, %2" : "=v"(r) : "v"(x), "v"(y));
    return r;
}

// Single-step row_shr:D (D=1..15), bound_ctrl zero-fill, applied to all 4
// dwords of a bf16x8 fragment. Bv[d](nh,qd) = Bv[0](nh-d,qd), 0 for nh<d.
// 15 INDEPENDENT ops (validated R13/R14).
template<int CTRL>
__device__ __forceinline__ short8x dpp_shr(short8x v) {
    v4i p = __builtin_bit_cast(v4i, v);
    v4i q;
    q.x = __builtin_amdgcn_update_dpp(0, p.x, CTRL, 0xf, 0xf, true);
    q.y = __builtin_amdgcn_update_dpp(0, p.y, CTRL, 0xf, 0xf, true);
    q.z = __builtin_amdgcn_update_dpp(0, p.z, CTRL, 0xf, 0xf, true);
    q.w = __builtin_amdgcn_update_dpp(0, p.w, CTRL, 0xf, 0xf, true);
    return __builtin_bit_cast(short8x, q);
}

// R16: one wave (64 thr) per channel, NO barriers. Structure = R0 exactly
// (B-read at loop top, 4 MFMA chains x depth 8) -- R13/R15 structural
// variants measured neutral, R14 (+VALU) regressed 1:1 with VALU cycles.
// This round is purely SUBTRACTIVE on the VALU stream:
//  (a) all in-loop expf -> native v_exp_f32 via exp2: exp(-P1*s) ==
//      exp2(P1L*s) with P1L[u] = (1-P2[u])*log2e precomputed (1 mul + 1
//      trans op vs ~14-op libm expf);
//  (b) all bf16 packing -> v_cvt_pk_bf16_f32 (1 op vs ~7).
// Block-Toeplitz MFMA (validated R8/R9): Qn[32I+i] = sum_d sum_k
// G_d[i][k]*Qsrc[32(I-d)+k], G_d[i][k] = g(32d+i-k), g = DT*q_n reversed,
// zero for negative arg. gt copy kk pos w holds r[w+kk] so every A-read is
// one aligned ds_read_b128; DPP bound_ctrl zeros give the B boundary.
__global__ __launch_bounds__(64, 1) void outage_kernel(
    const float* __restrict__ pathloss,
    const float* __restrict__ powers,
    float* __restrict__ out)
{
    __shared__ __align__(16) unsigned short gt[2][8][544];  // 8 shifted copies, ping-pong
    __shared__ __align__(16) unsigned short Qb[2][1024];    // [0,512)=zeros, [512,1024)=data

    const int lane = threadIdx.x;
    const int c = blockIdx.x, b = c >> 6, l = c & 63;
    const int nh = lane & 15;          // MFMA m / n index
    const int qd = lane >> 4;          // MFMA quad (k-group)

    // ---- inline prep: rowsum + diag of pathloss row l (coalesced) ----
    const float pl = pathloss[l * LL + lane];
    float rs = pl;
    #pragma unroll
    for (int mk = 1; mk < 64; mk <<= 1) rs += __shfl_xor(rs, mk, 64);
    const float dg   = __shfl(pl, l, 64);
    const float dsum = rs - dg;

    // per-lane time constants, tau = 8*lane + u:
    //   P2[u]  = 2^(tau*DT)
    //   P1L[u] = (1 - P2[u]) * log2e   (so exp(-(P2-1)*s) == exp2(P1L*s))
    float P2[8], P1L[8];
    #pragma unroll
    for (int u = 0; u < 8; ++u) {
        float e = __builtin_amdgcn_exp2f((8 * lane + u) * DTC);
        P2[u]  = e;
        P1L[u] = (1.f - e) * LOG2E;
    }

    // zero Q prefixes (1 KiB each) and gt tails [512,544) of both buffers
    *((uint4*)&Qb[0][0] + lane) = uint4{0u, 0u, 0u, 0u};
    *((uint4*)&Qb[1][0] + lane) = uint4{0u, 0u, 0u, 0u};
    {
        const int bb = lane >> 5, w = lane & 31;
        #pragma unroll
        for (int k = 0; k < 8; ++k) gt[bb][k][512 + w] = 0;
    }

    // Q0(tau) = 1 - exp(-(2^{tau*DT}-1)*s0) = 1 - exp2(P1L*s0), bf16 into Qb[0]
    const float p0 = powers[(b * NN + 0) * LL + l];
    const float s0 = dg * p0 / (p0 * dsum + NOISEC);
    float q7;
    {
        float v[8];
        #pragma unroll
        for (int u = 0; u < 8; ++u) v[u] = 1.f - __builtin_amdgcn_exp2f(P1L[u] * s0);
        q7 = v[7];                                  // lane 63: Q0[511]
        uint4 d4 = { cvt_pk_bf16(v[0], v[1]), cvt_pk_bf16(v[2], v[3]),
                     cvt_pk_bf16(v[4], v[5]), cvt_pk_bf16(v[6], v[7]) };
        *(uint4*)&Qb[0][512 + 8 * lane] = d4;
    }

    const float p1v = powers[(b * NN + 1) * LL + l];
    float lossCh = 1.f + p0 + (p1v + 1.f) * q7;     // only lane 63's is used

    // fill the 8 shifted copies of r[tau] = DT*q_n(tau) for a step into buf
    auto fill_g = [&](int buf, float p) {
        float s  = dg * p / (p * dsum + NOISEC);
        float cm = s * LN2C * DTC;
        unsigned F[8];                               // F[0..3] own pairs, F[4..7] neighbor
        #pragma unroll
        for (int w = 0; w < 4; ++w) {
            float a  = __builtin_amdgcn_exp2f(P1L[2 * w]     * s) * (P2[2 * w]     * cm);
            float bb = __builtin_amdgcn_exp2f(P1L[2 * w + 1] * s) * (P2[2 * w + 1] * cm);
            F[w] = cvt_pk_bf16(a, bb);
        }
        #pragma unroll
        for (int w = 0; w < 4; ++w) {
            unsigned t = (unsigned)__shfl_down((int)F[w], 1, 64);
            F[4 + w] = (lane == 63) ? 0u : t;       // tau >= 512 -> 0
        }
        unsigned E[7];                               // odd-phase pairs
        #pragma unroll
        for (int j = 0; j < 7; ++j) E[j] = (F[j] >> 16) | (F[j + 1] << 16);
        #pragma unroll
        for (int k = 0; k < 8; ++k) {               // copy k pos 8L+w holds r[8L+w+k]
            uint4 d4;
            if ((k & 1) == 0) d4 = uint4{F[k / 2], F[k / 2 + 1], F[k / 2 + 2], F[k / 2 + 3]};
            else              d4 = uint4{E[k / 2], E[k / 2 + 1], E[k / 2 + 2], E[k / 2 + 3]};
            *(uint4*)&gt[buf][k][8 * lane] = d4;
        }
    };
    fill_g(1, p1v);                                 // g-table for step n=1

    const int kk    = (7 - nh) & 7;                 // this lane's copy index
    const int baseA = 511 - nh + 8 * qd - kk;       // == 0 mod 8 (16B aligned)
    const int baseB = 512 + 32 * nh + 8 * qd;
    const int dstw  = 512 + 32 * nh + 4 * qd;       // +16 for M-tile 1

    float pnext = powers[(b * NN + 2) * LL + l];    // pw[n+1] entering n=1

    for (int n = 1; n < NN; ++n) {
        const unsigned short* psrc = &Qb[(n + 1) & 1][0];   // == (n-1)&1
        const unsigned short* pg   = &gt[n & 1][kk][0];
        unsigned short* pdst       = &Qb[n & 1][0];

        // issue next-next power load early (lands during this step's work)
        float pfut = 0.f;
        if (n <= NN - 3) pfut = powers[(b * NN + n + 2) * LL + l];

        // ---- B: one ds_read_b128 + 15 INDEPENDENT row_shr:d derivations ----
        short8x Bv[16];
        Bv[0]  = *(const short8x*)&psrc[baseB];
        Bv[1]  = dpp_shr<0x111>(Bv[0]);
        Bv[2]  = dpp_shr<0x112>(Bv[0]);
        Bv[3]  = dpp_shr<0x113>(Bv[0]);
        Bv[4]  = dpp_shr<0x114>(Bv[0]);
        Bv[5]  = dpp_shr<0x115>(Bv[0]);
        Bv[6]  = dpp_shr<0x116>(Bv[0]);
        Bv[7]  = dpp_shr<0x117>(Bv[0]);
        Bv[8]  = dpp_shr<0x118>(Bv[0]);
        Bv[9]  = dpp_shr<0x119>(Bv[0]);
        Bv[10] = dpp_shr<0x11A>(Bv[0]);
        Bv[11] = dpp_shr<0x11B>(Bv[0]);
        Bv[12] = dpp_shr<0x11C>(Bv[0]);
        Bv[13] = dpp_shr<0x11D>(Bv[0]);
        Bv[14] = dpp_shr<0x11E>(Bv[0]);
        Bv[15] = dpp_shr<0x11F>(Bv[0]);

        // ---- A operands for this step (32 x ds_read_b128) ----
        short8x A0v[16], A1v[16];
        #pragma unroll
        for (int d = 0; d < 16; ++d) {
            A0v[d] = *(const short8x*)&pg[baseA - 32 * d];
            A1v[d] = *(const short8x*)&pg[baseA - 32 * d - 16];
        }

        // ---- fill g-table for step n+1 (independent buffer) under the
        //      MFMA shadow; uses pnext loaded one iteration ago ----
        if (n < NN - 1) fill_g((n + 1) & 1, pnext);

        // ---- 4 independent MFMA chains (d even/odd x 2 M-tiles) ----
        f32x4 acc0a = {0.f, 0.f, 0.f, 0.f}, acc0b = {0.f, 0.f, 0.f, 0.f};
        f32x4 acc1a = {0.f, 0.f, 0.f, 0.f}, acc1b = {0.f, 0.f, 0.f, 0.f};
        #pragma unroll
        for (int d = 0; d < 16; d += 2) {
            acc0a = __builtin_amdgcn_mfma_f32_16x16x32_bf16(A0v[d],     Bv[d],     acc0a, 0, 0, 0);
            acc1a = __builtin_amdgcn_mfma_f32_16x16x32_bf16(A1v[d],     Bv[d],     acc1a, 0, 0, 0);
            acc0b = __builtin_amdgcn_mfma_f32_16x16x32_bf16(A0v[d + 1], Bv[d + 1], acc0b, 0, 0, 0);
            acc1b = __builtin_amdgcn_mfma_f32_16x16x32_bf16(A1v[d + 1], Bv[d + 1], acc1b, 0, 0, 0);
        }
        f32x4 acc0 = acc0a + acc0b;
        f32x4 acc1 = acc1a + acc1b;

        // write Qn (bf16): lane holds rows 4qd..4qd+3 of both M-tiles, col nh
        *(uint2*)&pdst[dstw]      = uint2{cvt_pk_bf16(acc0.x, acc0.y), cvt_pk_bf16(acc0.z, acc0.w)};
        *(uint2*)&pdst[dstw + 16] = uint2{cvt_pk_bf16(acc1.x, acc1.y), cvt_pk_bf16(acc1.z, acc1.w)};

        // loss tap: lane 63 acc1.w == Qn[511] (row 31, col 15), fp32 precision
        float wgt = (n < NN - 1) ? (pnext + 1.f) : 1.f;   // pnext == pw[n+1]
        lossCh += wgt * acc1.w;
        pnext = pfut;
    }

    if (lane == 63) atomicAdd(out, lossCh);
}

extern "C" void kernel_launch(void* const* d_in, const int* in_sizes, int n_in,
                              void* d_out, int out_size, void* d_ws, size_t ws_size,
                              hipStream_t stream) {
    const float* pathloss = (const float*)d_in[0];
    const float* powers   = (const float*)d_in[1];
    float* outp = (float*)d_out;

    (void)hipMemsetAsync(d_out, 0, sizeof(float) * out_size, stream);
    outage_kernel<<<16 * LL, 64, 0, stream>>>(pathloss, powers, outp);
}